// Round 11
// baseline (127.838 us; speedup 1.0000x reference)
//
#include <hip/hip_runtime.h>

#define EMBED 2048
#define HEAD 128
#define BATCH 8
#define SEQ 2048

typedef __attribute__((ext_vector_type(4))) float f32x4;
typedef __attribute__((ext_vector_type(8))) __bf16 bf16x8;
typedef __attribute__((ext_vector_type(8))) short short8;

static __device__ __forceinline__ ushort f2bf(float x){
    unsigned u = __float_as_uint(x);
    u += 0x7fffu + ((u >> 16) & 1u);
    return (ushort)(u >> 16);
}

#define MFMA16(a,b,c) __builtin_amdgcn_mfma_f32_16x16x32_bf16((a),(b),(c),0,0,0)

#define GLL16(g, l) __builtin_amdgcn_global_load_lds( \
    (const __attribute__((address_space(1))) void*)(g), \
    (__attribute__((address_space(3))) void*)(l), 16, 0, 0)

// ---------------- prep: W [2048][128] f32 -> W^T [3*128][2048] bf16 (LDS transpose) ----------------
__global__ __launch_bounds__(256) void prep_wt(const float* __restrict__ Wq,
                                               const float* __restrict__ Wk,
                                               const float* __restrict__ Wv,
                                               ushort* __restrict__ wt){
    __shared__ float ld[64][129];
    const int w  = blockIdx.y;
    const int k0 = blockIdx.x * 64;
    const int tid = threadIdx.x;
    const float* W = (w == 0) ? Wq : ((w == 1) ? Wk : Wv);
    #pragma unroll
    for (int ii = 0; ii < 32; ii++){
        int idx = tid + 256 * ii;
        int row = idx >> 7, col = idx & 127;
        ld[row][col] = W[(size_t)(k0 + row) * HEAD + col];
    }
    __syncthreads();
    int n  = tid >> 1;
    int kh = (tid & 1) * 32;
    __attribute__((aligned(16))) ushort tmp[32];
    #pragma unroll
    for (int ii = 0; ii < 32; ii++) tmp[ii] = f2bf(ld[kh + ii][n]);
    ushort* dst = wt + (size_t)(w * HEAD + n) * EMBED + k0 + kh;
    #pragma unroll
    for (int q = 0; q < 4; q++)
        *(short8*)(dst + q * 8) = *(const short8*)(tmp + q * 8);
}

// ---------------- Fused QKV GEMM: [16384x2048]x[2048x384], attn-style pipelined loop ----------------
// BM=64, BN=192 (n-split x2), BK=64, 256 thr / 4 waves (wave tile 64m x 48n). Grid (2,256)=512 = 2/CU.
// Loop: [bar] ds_write x(kt) | issue x(kt+1) + GLL W(kt+1) | vmcnt(10)+lgkm0+s_barrier | MFMA | s_barrier.
// No vmcnt(0) drain in the loop: W(kt)'s GLL latency hides under iter kt-1's compute phase.
__global__ __launch_bounds__(256, 2) void qkv_gemm(const float* __restrict__ x,
                                                   const ushort* __restrict__ wt,
                                                   const float* __restrict__ bq,
                                                   const float* __restrict__ bk,
                                                   const float* __restrict__ bv,
                                                   ushort* __restrict__ Qb,
                                                   ushort* __restrict__ Kb,
                                                   ushort* __restrict__ Vt){
    __shared__ char smem[58368];
    // xs        = smem                [64][144B] padded bf16 (single buffer)
    // wl(buf i) = smem + 9216 + i*24576   [192][128B] linear, chunk-swizzled (double buffer)
    float* ts = (float*)smem;              // epilogue V transpose overlay [64][132] f32

    const int half  = blockIdx.x;
    const int mtile = blockIdx.y;
    const int tid   = threadIdx.x;
    const int lane  = tid & 63;
    const int wid   = tid >> 6;            // 0..3 : pure n-split
    const int l15   = lane & 15, lhi = lane >> 4;
    const int xrow0 = mtile * 64;

    const int srow = tid >> 3;             // 0..31 (+32 for 2nd chunk)
    const int ssub = tid & 7;              // 8-f32 chunk within row

    const ushort* wsrc_base = wt + (size_t)(half * 192) * EMBED;
    const int grow = lane >> 3;            // gll: row within 8-row group
    const int gch  = lane & 7;             // gll: 16B chunk

    char* xs = smem;

    f32x4 acc[4][3];
    #pragma unroll
    for (int i = 0; i < 4; i++)
        #pragma unroll
        for (int j = 0; j < 3; j++) acc[i][j] = (f32x4){0.f,0.f,0.f,0.f};

    const int NK = EMBED / 64;
    float4 xr[2][2];

    // ---- prologue: issue x(0) loads + GLL W(0) -> buf0 ----
    {
        const float* xp = x + (size_t)xrow0 * EMBED;
        #pragma unroll
        for (int h = 0; h < 2; h++){
            xr[h][0] = *(const float4*)(xp + (size_t)(srow + 32*h) * EMBED + ssub * 8);
            xr[h][1] = *(const float4*)(xp + (size_t)(srow + 32*h) * EMBED + ssub * 8 + 4);
        }
        #pragma unroll
        for (int g = 0; g < 6; g++){
            int r0  = wid * 48 + g * 8;
            int row = r0 + grow;
            GLL16(wsrc_base + (size_t)row * EMBED + ((gch ^ grow) * 8), smem + 9216 + r0 * 128);
        }
    }

    for (int kt = 0; kt < NK; ++kt){
        char* wl_c = smem + 9216 + (kt & 1) * 24576;
        char* wl_n = smem + 9216 + ((kt + 1) & 1) * 24576;

        // 1) x(kt) regs -> LDS (compiler auto-waits only those 4 loads)
        #pragma unroll
        for (int h = 0; h < 2; h++){
            __attribute__((aligned(16))) ushort t8[8];
            t8[0]=f2bf(xr[h][0].x); t8[1]=f2bf(xr[h][0].y); t8[2]=f2bf(xr[h][0].z); t8[3]=f2bf(xr[h][0].w);
            t8[4]=f2bf(xr[h][1].x); t8[5]=f2bf(xr[h][1].y); t8[6]=f2bf(xr[h][1].z); t8[7]=f2bf(xr[h][1].w);
            *(short8*)(xs + (srow + 32*h) * 144 + ssub * 16) = *(const short8*)t8;
        }
        // 2) issue next tile: x(kt+1) loads + GLL W(kt+1) (stay in flight through the barrier)
        if (kt < NK - 1){
            const float* xp = x + (size_t)xrow0 * EMBED + (kt + 1) * 64;
            #pragma unroll
            for (int h = 0; h < 2; h++){
                xr[h][0] = *(const float4*)(xp + (size_t)(srow + 32*h) * EMBED + ssub * 8);
                xr[h][1] = *(const float4*)(xp + (size_t)(srow + 32*h) * EMBED + ssub * 8 + 4);
            }
            const ushort* wsrc = wsrc_base + (kt + 1) * 64;
            #pragma unroll
            for (int g = 0; g < 6; g++){
                int r0  = wid * 48 + g * 8;
                int row = r0 + grow;
                GLL16(wsrc + (size_t)row * EMBED + ((gch ^ grow) * 8), wl_n + r0 * 128);
            }
            // wait for W(kt)'s 6 GLLs (issued last iter); 10 newer ops (4 x-loads + 6 GLLs) stay in flight
            asm volatile("s_waitcnt vmcnt(10)" ::: "memory");
        } else {
            asm volatile("s_waitcnt vmcnt(0)" ::: "memory");
        }
        asm volatile("s_waitcnt lgkmcnt(0)" ::: "memory");   // x ds_writes visible
        __builtin_amdgcn_s_barrier();
        __builtin_amdgcn_sched_barrier(0);

        // 3) compute(kt)
        #pragma unroll
        for (int kc = 0; kc < 2; kc++){
            bf16x8 af[4], bfj[3];
            #pragma unroll
            for (int i = 0; i < 4; i++)
                af[i] = *(const bf16x8*)(xs + (i*16 + l15) * 144 + kc*64 + lhi*16);
            #pragma unroll
            for (int j = 0; j < 3; j++){
                int row = wid * 48 + j * 16 + l15;
                bfj[j] = *(const bf16x8*)(wl_c + row * 128 + (((kc*4 + lhi) ^ (l15 & 7)) * 16));
            }
            #pragma unroll
            for (int i = 0; i < 4; i++)
                #pragma unroll
                for (int j = 0; j < 3; j++)
                    acc[i][j] = MFMA16(af[i], bfj[j], acc[i][j]);
        }
        // 4) readers done before next iter's ds_write/GLL overwrite (plain barrier, no drain)
        __builtin_amdgcn_s_barrier();
    }

    // ---- epilogue (r4-verified) ----
    float bval[3];
    #pragma unroll
    for (int j = 0; j < 3; j++){
        int c = half * 192 + wid * 48 + j * 16 + l15;
        bval[j] = (c < 128) ? bq[c] : ((c < 256) ? bk[c - 128] : bv[c - 256]);
    }
    #pragma unroll
    for (int j = 0; j < 3; j++){
        int cb = half * 192 + wid * 48 + j * 16;
        if (cb < 256){
            ushort* dst = (cb < 128) ? Qb : Kb;
            int cl = (cb < 128) ? (cb + l15) : (cb - 128 + l15);
            #pragma unroll
            for (int i = 0; i < 4; i++)
                #pragma unroll
                for (int r = 0; r < 4; r++)
                    dst[(size_t)(mtile*64 + i*16 + lhi*4 + r) * HEAD + cl] = f2bf(acc[i][j][r] + bval[j]);
        }
    }
    if (half == 1){
        __syncthreads();
        #pragma unroll
        for (int j = 0; j < 3; j++){
            int cb = 192 + wid * 48 + j * 16;
            if (cb >= 256){
                int vc = cb - 256 + l15;
                #pragma unroll
                for (int i = 0; i < 4; i++)
                    #pragma unroll
                    for (int r = 0; r < 4; r++)
                        ts[(i*16 + lhi*4 + r) * 132 + vc] = acc[i][j][r] + bval[j];
            }
        }
        __syncthreads();
        int n  = tid >> 1;
        int mc = (tid & 1) * 32;
        int bb = mtile >> 5;
        int trow = (mtile & 31) * 64 + mc;
        __attribute__((aligned(16))) ushort tmp[32];
        #pragma unroll
        for (int ii = 0; ii < 32; ii++) tmp[ii] = f2bf(ts[(mc + ii) * 132 + n]);
        ushort* dst = Vt + ((size_t)(bb * HEAD + n)) * SEQ + trow;
        #pragma unroll
        for (int q = 0; q < 4; q++)
            *(short8*)(dst + q * 8) = *(const short8*)(tmp + q * 8);
    }
}

// ---------------- Flash attention, causal, kv-split x2, async-staged ----------------
__global__ __launch_bounds__(256) void attn(const ushort* __restrict__ Qb,
                                            const ushort* __restrict__ Kb,
                                            const ushort* __restrict__ Vt,
                                            float* __restrict__ po,
                                            float* __restrict__ pm,
                                            float* __restrict__ pl){
    __shared__ char smem[40960];
    char* Ks = smem;            // [64 kv][256 B] chunk-swizzled (^row&15)
    char* Vs = smem + 16384;    // [128 d][128 B] chunk-swizzled (^d&7)
    char* Ps = smem + 32768;    // 4 waves x [16 q][128 B] chunk-swizzled (^q&7)

    const int slot = blockIdx.x;
    const int b    = blockIdx.y;
    const int qi   = slot >> 1;
    const int qt   = (b < 4) ? qi : (31 - qi);     // anti-correlated pairing
    const int half = slot & 1;
    const int NT   = qt + 1;
    const int tmid = (NT + 1) >> 1;
    const int t0   = half ? tmid : 0;
    const int t1   = half ? NT : tmid;

    const int qb    = qt * 64;
    const int tid   = threadIdx.x;
    const int lane  = tid & 63, wid = tid >> 6;
    const int l15   = lane & 15, lhi = lane >> 4;
    const float scale = 0.08838834764831845f;   // 1/sqrt(128)

    bf16x8 qf[4];
    {
        const ushort* qp = Qb + ((size_t)(b * SEQ + qb + wid * 16 + l15)) * HEAD;
        #pragma unroll
        for (int kc = 0; kc < 4; kc++)
            qf[kc] = *(const bf16x8*)(qp + kc * 32 + lhi * 8);
    }

    f32x4 o[8];
    #pragma unroll
    for (int d = 0; d < 8; d++) o[d] = (f32x4){0.f,0.f,0.f,0.f};
    float mr[4] = {-1e30f,-1e30f,-1e30f,-1e30f};
    float lr[4] = {0.f,0.f,0.f,0.f};

    char* Pw = Ps + wid * 2048;

    const int krow = tid >> 4, kch = tid & 15;   // K stage coords
    const int vd   = tid >> 3, vch = tid & 7;    // V stage coords

    short8 kr[4], vr[4];
    {
        const int kvb = t0 * 64;
        #pragma unroll
        for (int j = 0; j < 4; j++)
            kr[j] = *(const short8*)(Kb + ((size_t)(b * SEQ + kvb + krow + 16*j)) * HEAD + kch * 8);
        #pragma unroll
        for (int j = 0; j < 4; j++)
            vr[j] = *(const short8*)(Vt + ((size_t)(b * HEAD + vd + 32*j)) * SEQ + kvb + vch * 8);
    }

    for (int t = t0; t < t1; ++t){
        __syncthreads();
        #pragma unroll
        for (int j = 0; j < 4; j++){
            int row = krow + 16*j;
            *(short8*)(Ks + row * 256 + ((kch ^ (row & 15)) * 16)) = kr[j];
        }
        #pragma unroll
        for (int j = 0; j < 4; j++){
            int d = vd + 32*j;
            *(short8*)(Vs + d * 128 + ((vch ^ (d & 7)) * 16)) = vr[j];
        }
        if (t + 1 < t1){
            const int kvb2 = (t + 1) * 64;
            #pragma unroll
            for (int j = 0; j < 4; j++)
                kr[j] = *(const short8*)(Kb + ((size_t)(b * SEQ + kvb2 + krow + 16*j)) * HEAD + kch * 8);
            #pragma unroll
            for (int j = 0; j < 4; j++)
                vr[j] = *(const short8*)(Vt + ((size_t)(b * HEAD + vd + 32*j)) * SEQ + kvb2 + vch * 8);
        }
        asm volatile("s_waitcnt lgkmcnt(0)" ::: "memory");
        __builtin_amdgcn_s_barrier();
        __builtin_amdgcn_sched_barrier(0);

        const int kvb = t * 64;
        f32x4 s[4];
        #pragma unroll
        for (int ns = 0; ns < 4; ns++){
            s[ns] = (f32x4){0.f,0.f,0.f,0.f};
            int row = ns * 16 + l15;
            #pragma unroll
            for (int kc = 0; kc < 4; kc++){
                int ch = (kc * 4 + lhi) ^ (row & 15);
                bf16x8 bfr = *(const bf16x8*)(Ks + row * 256 + ch * 16);
                s[ns] = MFMA16(qf[kc], bfr, s[ns]);
            }
        }

        float mx[4];
        #pragma unroll
        for (int r = 0; r < 4; r++){
            #pragma unroll
            for (int ns = 0; ns < 4; ns++){
                float v = s[ns][r] * scale;
                if (t == qt){
                    int kvg = kvb + ns * 16 + l15;
                    int qg  = qb + wid * 16 + lhi * 4 + r;
                    if (kvg > qg) v = -1e30f;
                }
                s[ns][r] = v;
            }
            float m0 = fmaxf(fmaxf(s[0][r], s[1][r]), fmaxf(s[2][r], s[3][r]));
            m0 = fmaxf(m0, __shfl_xor(m0, 1));
            m0 = fmaxf(m0, __shfl_xor(m0, 2));
            m0 = fmaxf(m0, __shfl_xor(m0, 4));
            m0 = fmaxf(m0, __shfl_xor(m0, 8));
            mx[r] = m0;
        }
        float alpha[4];
        #pragma unroll
        for (int r = 0; r < 4; r++){
            float mn = fmaxf(mr[r], mx[r]);
            alpha[r] = __expf(mr[r] - mn);
            mr[r] = mn;
            float sum = 0.f;
            #pragma unroll
            for (int ns = 0; ns < 4; ns++){
                float p = __expf(s[ns][r] - mn);
                s[ns][r] = p;
                sum += p;
            }
            sum += __shfl_xor(sum, 1);
            sum += __shfl_xor(sum, 2);
            sum += __shfl_xor(sum, 4);
            sum += __shfl_xor(sum, 8);
            lr[r] = lr[r] * alpha[r] + sum;
        }
        #pragma unroll
        for (int d = 0; d < 8; d++)
            #pragma unroll
            for (int r = 0; r < 4; r++) o[d][r] *= alpha[r];

        #pragma unroll
        for (int ns = 0; ns < 4; ns++)
            #pragma unroll
            for (int r = 0; r < 4; r++){
                int row = lhi * 4 + r;
                int byteoff = row * 128 + (((ns * 16 + l15) * 2) ^ ((row & 7) << 4));
                *(ushort*)(Pw + byteoff) = f2bf(s[ns][r]);
            }
        asm volatile("s_waitcnt lgkmcnt(0)" ::: "memory");
        __builtin_amdgcn_sched_barrier(0);

        #pragma unroll
        for (int kc = 0; kc < 2; kc++){
            int abyte = l15 * 128 + ((kc * 64 + lhi * 16) ^ ((l15 & 7) << 4));
            bf16x8 af = *(const bf16x8*)(Pw + abyte);
            #pragma unroll
            for (int ds = 0; ds < 8; ds++){
                int drow = ds * 16 + l15;
                int bbyte = drow * 128 + ((kc * 64 + lhi * 16) ^ ((drow & 7) << 4));
                bf16x8 bfr = *(const bf16x8*)(Vs + bbyte);
                o[ds] = MFMA16(af, bfr, o[ds]);
            }
        }
    }

    float* pob = po + ((size_t)half * 16384 + (size_t)b * SEQ) * HEAD;
    #pragma unroll
    for (int r = 0; r < 4; r++){
        int q = qb + wid * 16 + lhi * 4 + r;
        #pragma unroll
        for (int ds = 0; ds < 8; ds++)
            pob[(size_t)q * HEAD + ds * 16 + l15] = o[ds][r];
        if (l15 == 0){
            pm[half * 16384 + b * SEQ + q] = mr[r];
            pl[half * 16384 + b * SEQ + q] = lr[r];
        }
    }
}

// ---------------- merge two kv-halves ----------------
__global__ __launch_bounds__(256) void merge(const float* __restrict__ po,
                                             const float* __restrict__ pm,
                                             const float* __restrict__ pl,
                                             float* __restrict__ out){
    int g = blockIdx.x * 256 + threadIdx.x;
    int row = g >> 2;
    int dq  = (g & 3) * 32;
    float m0 = pm[row], m1 = pm[16384 + row];
    float l0 = pl[row], l1 = pl[16384 + row];
    float M  = fmaxf(m0, m1);
    float w0 = __expf(m0 - M), w1 = __expf(m1 - M);
    float inv = 1.0f / (w0 * l0 + w1 * l1);
    const float4* p0 = (const float4*)(po + (size_t)row * HEAD + dq);
    const float4* p1 = (const float4*)(po + (size_t)(16384 + row) * HEAD + dq);
    float4* op = (float4*)(out + (size_t)row * HEAD + dq);
    #pragma unroll
    for (int i = 0; i < 8; i++){
        float4 a = p0[i], c = p1[i];
        float4 r;
        r.x = (w0*a.x + w1*c.x) * inv;
        r.y = (w0*a.y + w1*c.y) * inv;
        r.z = (w0*a.z + w1*c.z) * inv;
        r.w = (w0*a.w + w1*c.w) * inv;
        op[i] = r;
    }
}

extern "C" void kernel_launch(void* const* d_in, const int* in_sizes, int n_in,
                              void* d_out, int out_size, void* d_ws, size_t ws_size,
                              hipStream_t stream){
    const float* x  = (const float*)d_in[0];
    const float* Wq = (const float*)d_in[1];
    const float* bq = (const float*)d_in[2];
    const float* Wk = (const float*)d_in[3];
    const float* bk = (const float*)d_in[4];
    const float* Wv = (const float*)d_in[5];
    const float* bv = (const float*)d_in[6];
    float* out = (float*)d_out;

    char* ws = (char*)d_ws;
    ushort* Qb = (ushort*)ws;                                  // 4 MB   [16384][128]
    ushort* Kb = (ushort*)(ws + (size_t)4  * 1024 * 1024);     // 4 MB   [16384][128]
    ushort* Vt = (ushort*)(ws + (size_t)8  * 1024 * 1024);     // 4 MB   [8][128][2048]
    ushort* Wt = (ushort*)(ws + (size_t)12 * 1024 * 1024);     // 1.57MB [384][2048]
    float*  po = (float*) (ws + (size_t)14 * 1024 * 1024);     // 16.8MB [2][16384][128]
    float*  pm = (float*) (ws + (size_t)31 * 1024 * 1024);     // 131KB  [2][16384]
    float*  pl = (float*) (ws + (size_t)31 * 1024 * 1024 + 262144);

    prep_wt <<<dim3(32, 3), 256, 0, stream>>>(Wq, Wk, Wv, Wt);
    qkv_gemm<<<dim3(2, 256), 256, 0, stream>>>(x, Wt, bq, bk, bv, Qb, Kb, Vt);
    attn    <<<dim3(64, 8), 256, 0, stream>>>(Qb, Kb, Vt, po, pm, pl);
    merge   <<<256, 256, 0, stream>>>(po, pm, pl, out);
}

// Round 12
// 111.138 us; speedup vs baseline: 1.1503x; 1.1503x over previous
//
#include <hip/hip_runtime.h>

#define EMBED 2048
#define HEAD 128
#define BATCH 8
#define SEQ 2048

typedef __attribute__((ext_vector_type(4))) float f32x4;
typedef __attribute__((ext_vector_type(8))) __bf16 bf16x8;
typedef __attribute__((ext_vector_type(8))) short short8;

static __device__ __forceinline__ ushort f2bf(float x){
    unsigned u = __float_as_uint(x);
    u += 0x7fffu + ((u >> 16) & 1u);
    return (ushort)(u >> 16);
}

#define MFMA16(a,b,c) __builtin_amdgcn_mfma_f32_16x16x32_bf16((a),(b),(c),0,0,0)

#define GLL16(g, l) __builtin_amdgcn_global_load_lds( \
    (const __attribute__((address_space(1))) void*)(g), \
    (__attribute__((address_space(3))) void*)(l), 16, 0, 0)

// ---------------- prep: W [2048][128] f32 -> W^T [3*128][2048] bf16 (LDS transpose) ----------------
__global__ __launch_bounds__(256) void prep_wt(const float* __restrict__ Wq,
                                               const float* __restrict__ Wk,
                                               const float* __restrict__ Wv,
                                               ushort* __restrict__ wt){
    __shared__ float ld[64][129];
    const int w  = blockIdx.y;
    const int k0 = blockIdx.x * 64;
    const int tid = threadIdx.x;
    const float* W = (w == 0) ? Wq : ((w == 1) ? Wk : Wv);
    #pragma unroll
    for (int ii = 0; ii < 32; ii++){
        int idx = tid + 256 * ii;
        int row = idx >> 7, col = idx & 127;
        ld[row][col] = W[(size_t)(k0 + row) * HEAD + col];
    }
    __syncthreads();
    int n  = tid >> 1;
    int kh = (tid & 1) * 32;
    __attribute__((aligned(16))) ushort tmp[32];
    #pragma unroll
    for (int ii = 0; ii < 32; ii++) tmp[ii] = f2bf(ld[kh + ii][n]);
    ushort* dst = wt + (size_t)(w * HEAD + n) * EMBED + k0 + kh;
    #pragma unroll
    for (int q = 0; q < 4; q++)
        *(short8*)(dst + q * 8) = *(const short8*)(tmp + q * 8);
}

// ---------------- Fused QKV GEMM: [16384x2048]x[2048x384], BIG-ITER pipelined ----------------
// BM=128, BN=192 (n-split x2), BK=128 -> only 16 K-iters. Grid (2,128)=256 = 1 block/CU.
// 512 thr / 8 waves (2m x 4n; wave tile 64x48). LDS: x [128][272B] 34.8KB + W dbuf 2x48KB = 130KB.
// Loop: ds_write x(kt) | issue x(kt+1)x8 + GLL W(kt+1)x6 | vmcnt(14)+lgkm0+bar | 48 MFMA/wave | bar.
__global__ __launch_bounds__(512) void qkv_gemm(const float* __restrict__ x,
                                                const ushort* __restrict__ wt,
                                                const float* __restrict__ bq,
                                                const float* __restrict__ bk,
                                                const float* __restrict__ bv,
                                                ushort* __restrict__ Qb,
                                                ushort* __restrict__ Kb,
                                                ushort* __restrict__ Vt){
    __shared__ char smem[133120];
    // xs        = smem                 [128][272B] padded bf16 (single buffer)
    // wl(buf i) = smem + 34816 + i*49152   [192][256B] linear, chunk-swizzled (double buffer)
    float* ts = (float*)smem;               // epilogue V transpose overlay [128][132] f32

    const int half  = blockIdx.x;
    const int mtile = blockIdx.y;           // 0..127 (128 rows each)
    const int tid   = threadIdx.x;
    const int lane  = tid & 63;
    const int wid   = tid >> 6;             // 0..7
    const int l15   = lane & 15, lhi = lane >> 4;
    const int wm    = wid >> 2,  wn  = wid & 3;   // 2m x 4n
    const int xrow0 = mtile * 128;

    const int srow = tid >> 2;              // 0..127 x stage row
    const int sq   = tid & 3;               // quarter of the 128-k row (32 f32)

    const ushort* wsrc_base = wt + (size_t)(half * 192) * EMBED;
    const int grow = lane >> 4;             // gll: row within 4-row group
    const int gch  = lane & 15;             // gll: 16B chunk (16 per row at BK=128)

    char* xs = smem;

    f32x4 acc[4][3];
    #pragma unroll
    for (int i = 0; i < 4; i++)
        #pragma unroll
        for (int j = 0; j < 3; j++) acc[i][j] = (f32x4){0.f,0.f,0.f,0.f};

    const int NK = EMBED / 128;   // 16
    float4 xr[8];

    // ---- prologue: issue x(0) loads + GLL W(0) -> buf0 ----
    {
        const float* xp = x + (size_t)(xrow0 + srow) * EMBED + sq * 32;
        #pragma unroll
        for (int g = 0; g < 8; g++) xr[g] = *(const float4*)(xp + g * 4);
        #pragma unroll
        for (int g = 0; g < 6; g++){
            int r0  = wid * 24 + g * 4;
            int row = r0 + grow;
            GLL16(wsrc_base + (size_t)row * EMBED + ((gch ^ (row & 7)) * 8), smem + 34816 + r0 * 256);
        }
    }

    for (int kt = 0; kt < NK; ++kt){
        char* wl_c = smem + 34816 + (kt & 1) * 49152;
        char* wl_n = smem + 34816 + ((kt + 1) & 1) * 49152;

        // 1) x(kt) regs -> LDS bf16 (compiler auto-waits only the 8 x loads)
        #pragma unroll
        for (int c = 0; c < 4; c++){
            __attribute__((aligned(16))) ushort t8[8];
            t8[0]=f2bf(xr[2*c].x); t8[1]=f2bf(xr[2*c].y); t8[2]=f2bf(xr[2*c].z); t8[3]=f2bf(xr[2*c].w);
            t8[4]=f2bf(xr[2*c+1].x); t8[5]=f2bf(xr[2*c+1].y); t8[6]=f2bf(xr[2*c+1].z); t8[7]=f2bf(xr[2*c+1].w);
            *(short8*)(xs + srow * 272 + sq * 64 + c * 16) = *(const short8*)t8;
        }
        // 2) issue next tile (stays in flight through the barrier)
        if (kt < NK - 1){
            const float* xp = x + (size_t)(xrow0 + srow) * EMBED + (kt + 1) * 128 + sq * 32;
            #pragma unroll
            for (int g = 0; g < 8; g++) xr[g] = *(const float4*)(xp + g * 4);
            const ushort* wsrc = wsrc_base + (kt + 1) * 128;
            #pragma unroll
            for (int g = 0; g < 6; g++){
                int r0  = wid * 24 + g * 4;
                int row = r0 + grow;
                GLL16(wsrc + (size_t)row * EMBED + ((gch ^ (row & 7)) * 8), wl_n + r0 * 256);
            }
            // outstanding: [W(kt) x6, x(kt+1) x8, W(kt+1) x6] = 20 -> drain only W(kt)
            asm volatile("s_waitcnt vmcnt(14)" ::: "memory");
        } else {
            asm volatile("s_waitcnt vmcnt(0)" ::: "memory");
        }
        asm volatile("s_waitcnt lgkmcnt(0)" ::: "memory");
        __builtin_amdgcn_s_barrier();
        __builtin_amdgcn_sched_barrier(0);

        // 3) compute(kt): 4 x K=32 sub-steps
        #pragma unroll
        for (int kc = 0; kc < 4; kc++){
            bf16x8 af[4], bfj[3];
            #pragma unroll
            for (int i = 0; i < 4; i++)
                af[i] = *(const bf16x8*)(xs + (wm*64 + i*16 + l15) * 272 + kc*64 + lhi*16);
            #pragma unroll
            for (int j = 0; j < 3; j++){
                int row = wn*48 + j*16 + l15;
                bfj[j] = *(const bf16x8*)(wl_c + row * 256 + (((kc*4 + lhi) ^ (row & 7)) * 16));
            }
            #pragma unroll
            for (int i = 0; i < 4; i++)
                #pragma unroll
                for (int j = 0; j < 3; j++)
                    acc[i][j] = MFMA16(af[i], bfj[j], acc[i][j]);
        }
        // 4) readers done before next iter overwrites xs / wl_n (plain barrier, no drain)
        __builtin_amdgcn_s_barrier();
    }

    // ---- epilogue ----
    float bval[3];
    #pragma unroll
    for (int j = 0; j < 3; j++){
        int c = half * 192 + wn * 48 + j * 16 + l15;
        bval[j] = (c < 128) ? bq[c] : ((c < 256) ? bk[c - 128] : bv[c - 256]);
    }
    #pragma unroll
    for (int j = 0; j < 3; j++){
        int cb = half * 192 + wn * 48 + j * 16;   // 16-aligned; wholly within Q, K, or V
        if (cb < 256){
            ushort* dst = (cb < 128) ? Qb : Kb;
            int cl = (cb & 127) + l15;
            #pragma unroll
            for (int i = 0; i < 4; i++)
                #pragma unroll
                for (int r = 0; r < 4; r++){
                    int m = mtile*128 + wm*64 + i*16 + lhi*4 + r;
                    dst[(size_t)m * HEAD + cl] = f2bf(acc[i][j][r] + bval[j]);
                }
        }
    }
    __syncthreads();   // staging buffers dead; reuse as ts
    if (half == 1){
        #pragma unroll
        for (int j = 0; j < 3; j++){
            int cb = 192 + wn * 48 + j * 16;
            if (cb >= 256){
                int vc = cb - 256 + l15;
                #pragma unroll
                for (int i = 0; i < 4; i++)
                    #pragma unroll
                    for (int r = 0; r < 4; r++){
                        int ml = wm*64 + i*16 + lhi*4 + r;
                        ts[ml * 132 + vc] = acc[i][j][r] + bval[j];
                    }
            }
        }
    }
    __syncthreads();
    if (half == 1){
        // transpose out: V [128 rows][128 cols] -> Vt [8][128][2048]
        int n  = tid >> 2;              // 0..127 V col
        int mc = (tid & 3) * 32;        // 32-row group
        int bb = mtile >> 4;            // 16 mtiles (128 rows) per batch
        int trow = (mtile & 15) * 128 + mc;
        __attribute__((aligned(16))) ushort tmp[32];
        #pragma unroll
        for (int ii = 0; ii < 32; ii++) tmp[ii] = f2bf(ts[(mc + ii) * 132 + n]);
        ushort* dst = Vt + ((size_t)(bb * HEAD + n)) * SEQ + trow;
        #pragma unroll
        for (int q = 0; q < 4; q++)
            *(short8*)(dst + q * 8) = *(const short8*)(tmp + q * 8);
    }
}

// ---------------- Flash attention, causal, kv-split x2, async-staged ----------------
__global__ __launch_bounds__(256) void attn(const ushort* __restrict__ Qb,
                                            const ushort* __restrict__ Kb,
                                            const ushort* __restrict__ Vt,
                                            float* __restrict__ po,
                                            float* __restrict__ pm,
                                            float* __restrict__ pl){
    __shared__ char smem[40960];
    char* Ks = smem;            // [64 kv][256 B] chunk-swizzled (^row&15)
    char* Vs = smem + 16384;    // [128 d][128 B] chunk-swizzled (^d&7)
    char* Ps = smem + 32768;    // 4 waves x [16 q][128 B] chunk-swizzled (^q&7)

    const int slot = blockIdx.x;
    const int b    = blockIdx.y;
    const int qi   = slot >> 1;
    const int qt   = (b < 4) ? qi : (31 - qi);     // anti-correlated pairing
    const int half = slot & 1;
    const int NT   = qt + 1;
    const int tmid = (NT + 1) >> 1;
    const int t0   = half ? tmid : 0;
    const int t1   = half ? NT : tmid;

    const int qb    = qt * 64;
    const int tid   = threadIdx.x;
    const int lane  = tid & 63, wid = tid >> 6;
    const int l15   = lane & 15, lhi = lane >> 4;
    const float scale = 0.08838834764831845f;   // 1/sqrt(128)

    bf16x8 qf[4];
    {
        const ushort* qp = Qb + ((size_t)(b * SEQ + qb + wid * 16 + l15)) * HEAD;
        #pragma unroll
        for (int kc = 0; kc < 4; kc++)
            qf[kc] = *(const bf16x8*)(qp + kc * 32 + lhi * 8);
    }

    f32x4 o[8];
    #pragma unroll
    for (int d = 0; d < 8; d++) o[d] = (f32x4){0.f,0.f,0.f,0.f};
    float mr[4] = {-1e30f,-1e30f,-1e30f,-1e30f};
    float lr[4] = {0.f,0.f,0.f,0.f};

    char* Pw = Ps + wid * 2048;

    const int krow = tid >> 4, kch = tid & 15;   // K stage coords
    const int vd   = tid >> 3, vch = tid & 7;    // V stage coords

    short8 kr[4], vr[4];
    {
        const int kvb = t0 * 64;
        #pragma unroll
        for (int j = 0; j < 4; j++)
            kr[j] = *(const short8*)(Kb + ((size_t)(b * SEQ + kvb + krow + 16*j)) * HEAD + kch * 8);
        #pragma unroll
        for (int j = 0; j < 4; j++)
            vr[j] = *(const short8*)(Vt + ((size_t)(b * HEAD + vd + 32*j)) * SEQ + kvb + vch * 8);
    }

    for (int t = t0; t < t1; ++t){
        __syncthreads();
        #pragma unroll
        for (int j = 0; j < 4; j++){
            int row = krow + 16*j;
            *(short8*)(Ks + row * 256 + ((kch ^ (row & 15)) * 16)) = kr[j];
        }
        #pragma unroll
        for (int j = 0; j < 4; j++){
            int d = vd + 32*j;
            *(short8*)(Vs + d * 128 + ((vch ^ (d & 7)) * 16)) = vr[j];
        }
        if (t + 1 < t1){
            const int kvb2 = (t + 1) * 64;
            #pragma unroll
            for (int j = 0; j < 4; j++)
                kr[j] = *(const short8*)(Kb + ((size_t)(b * SEQ + kvb2 + krow + 16*j)) * HEAD + kch * 8);
            #pragma unroll
            for (int j = 0; j < 4; j++)
                vr[j] = *(const short8*)(Vt + ((size_t)(b * HEAD + vd + 32*j)) * SEQ + kvb2 + vch * 8);
        }
        asm volatile("s_waitcnt lgkmcnt(0)" ::: "memory");
        __builtin_amdgcn_s_barrier();
        __builtin_amdgcn_sched_barrier(0);

        const int kvb = t * 64;
        f32x4 s[4];
        #pragma unroll
        for (int ns = 0; ns < 4; ns++){
            s[ns] = (f32x4){0.f,0.f,0.f,0.f};
            int row = ns * 16 + l15;
            #pragma unroll
            for (int kc = 0; kc < 4; kc++){
                int ch = (kc * 4 + lhi) ^ (row & 15);
                bf16x8 bfr = *(const bf16x8*)(Ks + row * 256 + ch * 16);
                s[ns] = MFMA16(qf[kc], bfr, s[ns]);
            }
        }

        float mx[4];
        #pragma unroll
        for (int r = 0; r < 4; r++){
            #pragma unroll
            for (int ns = 0; ns < 4; ns++){
                float v = s[ns][r] * scale;
                if (t == qt){
                    int kvg = kvb + ns * 16 + l15;
                    int qg  = qb + wid * 16 + lhi * 4 + r;
                    if (kvg > qg) v = -1e30f;
                }
                s[ns][r] = v;
            }
            float m0 = fmaxf(fmaxf(s[0][r], s[1][r]), fmaxf(s[2][r], s[3][r]));
            m0 = fmaxf(m0, __shfl_xor(m0, 1));
            m0 = fmaxf(m0, __shfl_xor(m0, 2));
            m0 = fmaxf(m0, __shfl_xor(m0, 4));
            m0 = fmaxf(m0, __shfl_xor(m0, 8));
            mx[r] = m0;
        }
        float alpha[4];
        #pragma unroll
        for (int r = 0; r < 4; r++){
            float mn = fmaxf(mr[r], mx[r]);
            alpha[r] = __expf(mr[r] - mn);
            mr[r] = mn;
            float sum = 0.f;
            #pragma unroll
            for (int ns = 0; ns < 4; ns++){
                float p = __expf(s[ns][r] - mn);
                s[ns][r] = p;
                sum += p;
            }
            sum += __shfl_xor(sum, 1);
            sum += __shfl_xor(sum, 2);
            sum += __shfl_xor(sum, 4);
            sum += __shfl_xor(sum, 8);
            lr[r] = lr[r] * alpha[r] + sum;
        }
        #pragma unroll
        for (int d = 0; d < 8; d++)
            #pragma unroll
            for (int r = 0; r < 4; r++) o[d][r] *= alpha[r];

        #pragma unroll
        for (int ns = 0; ns < 4; ns++)
            #pragma unroll
            for (int r = 0; r < 4; r++){
                int row = lhi * 4 + r;
                int byteoff = row * 128 + (((ns * 16 + l15) * 2) ^ ((row & 7) << 4));
                *(ushort*)(Pw + byteoff) = f2bf(s[ns][r]);
            }
        asm volatile("s_waitcnt lgkmcnt(0)" ::: "memory");
        __builtin_amdgcn_sched_barrier(0);

        #pragma unroll
        for (int kc = 0; kc < 2; kc++){
            int abyte = l15 * 128 + ((kc * 64 + lhi * 16) ^ ((l15 & 7) << 4));
            bf16x8 af = *(const bf16x8*)(Pw + abyte);
            #pragma unroll
            for (int ds = 0; ds < 8; ds++){
                int drow = ds * 16 + l15;
                int bbyte = drow * 128 + ((kc * 64 + lhi * 16) ^ ((drow & 7) << 4));
                bf16x8 bfr = *(const bf16x8*)(Vs + bbyte);
                o[ds] = MFMA16(af, bfr, o[ds]);
            }
        }
    }

    float* pob = po + ((size_t)half * 16384 + (size_t)b * SEQ) * HEAD;
    #pragma unroll
    for (int r = 0; r < 4; r++){
        int q = qb + wid * 16 + lhi * 4 + r;
        #pragma unroll
        for (int ds = 0; ds < 8; ds++)
            pob[(size_t)q * HEAD + ds * 16 + l15] = o[ds][r];
        if (l15 == 0){
            pm[half * 16384 + b * SEQ + q] = mr[r];
            pl[half * 16384 + b * SEQ + q] = lr[r];
        }
    }
}

// ---------------- merge two kv-halves ----------------
__global__ __launch_bounds__(256) void merge(const float* __restrict__ po,
                                             const float* __restrict__ pm,
                                             const float* __restrict__ pl,
                                             float* __restrict__ out){
    int g = blockIdx.x * 256 + threadIdx.x;
    int row = g >> 2;
    int dq  = (g & 3) * 32;
    float m0 = pm[row], m1 = pm[16384 + row];
    float l0 = pl[row], l1 = pl[16384 + row];
    float M  = fmaxf(m0, m1);
    float w0 = __expf(m0 - M), w1 = __expf(m1 - M);
    float inv = 1.0f / (w0 * l0 + w1 * l1);
    const float4* p0 = (const float4*)(po + (size_t)row * HEAD + dq);
    const float4* p1 = (const float4*)(po + (size_t)(16384 + row) * HEAD + dq);
    float4* op = (float4*)(out + (size_t)row * HEAD + dq);
    #pragma unroll
    for (int i = 0; i < 8; i++){
        float4 a = p0[i], c = p1[i];
        float4 r;
        r.x = (w0*a.x + w1*c.x) * inv;
        r.y = (w0*a.y + w1*c.y) * inv;
        r.z = (w0*a.z + w1*c.z) * inv;
        r.w = (w0*a.w + w1*c.w) * inv;
        op[i] = r;
    }
}

extern "C" void kernel_launch(void* const* d_in, const int* in_sizes, int n_in,
                              void* d_out, int out_size, void* d_ws, size_t ws_size,
                              hipStream_t stream){
    const float* x  = (const float*)d_in[0];
    const float* Wq = (const float*)d_in[1];
    const float* bq = (const float*)d_in[2];
    const float* Wk = (const float*)d_in[3];
    const float* bk = (const float*)d_in[4];
    const float* Wv = (const float*)d_in[5];
    const float* bv = (const float*)d_in[6];
    float* out = (float*)d_out;

    char* ws = (char*)d_ws;
    ushort* Qb = (ushort*)ws;                                  // 4 MB   [16384][128]
    ushort* Kb = (ushort*)(ws + (size_t)4  * 1024 * 1024);     // 4 MB   [16384][128]
    ushort* Vt = (ushort*)(ws + (size_t)8  * 1024 * 1024);     // 4 MB   [8][128][2048]
    ushort* Wt = (ushort*)(ws + (size_t)12 * 1024 * 1024);     // 1.57MB [384][2048]
    float*  po = (float*) (ws + (size_t)14 * 1024 * 1024);     // 16.8MB [2][16384][128]
    float*  pm = (float*) (ws + (size_t)31 * 1024 * 1024);     // 131KB  [2][16384]
    float*  pl = (float*) (ws + (size_t)31 * 1024 * 1024 + 262144);

    prep_wt <<<dim3(32, 3), 256, 0, stream>>>(Wq, Wk, Wv, Wt);
    qkv_gemm<<<dim3(2, 128), 512, 0, stream>>>(x, Wt, bq, bk, bv, Qb, Kb, Vt);
    attn    <<<dim3(64, 8), 256, 0, stream>>>(Qb, Kb, Vt, po, pm, pl);
    merge   <<<256, 256, 0, stream>>>(po, pm, pl, out);
}